// Round 1
// baseline (873.306 us; speedup 1.0000x reference)
//
#include <hip/hip_runtime.h>
#include <math.h>

#define B_    16
#define C_    512
#define T_    8192
#define T4_   (T_/4)          // 2048 float4 per (b,c) row
#define TILE  32              // t per block
#define TF4   (TILE/4)        // 8 float4 columns per tile
#define NT_   (T_/TILE)       // 256 tiles per batch chain
#define NBLK  (B_*NT_)        // 4096 blocks
#define NTHR  512

#define FLAG_AGG 1
#define FLAG_INC 2

__device__ __forceinline__ double wave_sum(double v) {
    #pragma unroll
    for (int m = 1; m < 64; m <<= 1) v += __shfl_xor(v, m, 64);
    return v;
}

// ---------------------------------------------------------------------------
// Single-pass fused kernel: per-(b,t)-tile channel sums -> decoupled-lookback
// cumulative prefix (double) -> normalize from registers. x read once, out
// written once; 512 MiB total HBM traffic.
//
// Thread layout: 512 thr = 8 waves. lane = t4(3b) | cg(3b); wave = wid.
//   channel  c = p*64 + wid*8 + cg   (p = 0..7)  -> covers all 512 channels
//   t-column    = j*8 + t4 (float4)              -> covers 32 t per block
// Deadlock safety: dynamic ticket => logical tile order == scheduling order.
// Cross-XCD visibility: agent-scope acquire/release atomics on flags+vals.
// ---------------------------------------------------------------------------
extern "C" __global__ void __launch_bounds__(NTHR, 4)
fused_cumnorm(const float* __restrict__ x,
              const float* __restrict__ gains,
              const float* __restrict__ bias,
              float* __restrict__ out,
              int* __restrict__ flags,           // [NBLK]
              unsigned int* __restrict__ ticket, // [1]
              double* __restrict__ vals)         // agg_s|agg_ss|inc_s|inc_ss x [NBLK]
{
    __shared__ float4 red_s[8][8];   // [wave][t4]
    __shared__ float4 red_ss[8][8];
    __shared__ float4 sh_mean[8];
    __shared__ float4 sh_rstd[8];
    __shared__ unsigned int sh_tk;

    const int tid  = threadIdx.x;
    const int lane = tid & 63;
    const int wid  = tid >> 6;          // 0..7
    const int t4   = lane & 7;          // float4 slot within tile
    const int cg   = lane >> 3;         // 0..7 channel subgroup within wave

    if (tid == 0) sh_tk = atomicAdd(ticket, 1u);
    __syncthreads();
    const int tk  = (int)sh_tk;
    const int b   = tk & (B_ - 1);      // interleave chains across tickets
    const int j   = tk >> 4;            // tile index within chain, 0..NT_-1
    const int rec = b * NT_ + j;

    const float4* x4 = (const float4*)x;
    const size_t tcol  = (size_t)j * TF4 + t4;
    const int    cbase = wid * 8 + cg;

    // ---- load x tile into registers, accumulate per-lane s/ss (fp32) ----
    float4 v[8];
    float4 s  = make_float4(0.f, 0.f, 0.f, 0.f);
    float4 ss = make_float4(0.f, 0.f, 0.f, 0.f);
    #pragma unroll
    for (int p = 0; p < 8; ++p) {
        const int c = p * 64 + cbase;
        float4 xv = x4[(size_t)(b * C_ + c) * T4_ + tcol];
        v[p] = xv;
        s.x += xv.x; s.y += xv.y; s.z += xv.z; s.w += xv.w;
        ss.x += xv.x * xv.x; ss.y += xv.y * xv.y;
        ss.z += xv.z * xv.z; ss.w += xv.w * xv.w;
    }
    // reduce over cg (lane bits 3..5) within wave
    #pragma unroll
    for (int m = 8; m < 64; m <<= 1) {
        s.x  += __shfl_xor(s.x,  m, 64); s.y  += __shfl_xor(s.y,  m, 64);
        s.z  += __shfl_xor(s.z,  m, 64); s.w  += __shfl_xor(s.w,  m, 64);
        ss.x += __shfl_xor(ss.x, m, 64); ss.y += __shfl_xor(ss.y, m, 64);
        ss.z += __shfl_xor(ss.z, m, 64); ss.w += __shfl_xor(ss.w, m, 64);
    }
    if (lane < 8) { red_s[wid][t4] = s; red_ss[wid][t4] = ss; }
    __syncthreads();

    if (wid == 0) {
        // cross-wave reduce: lane -> (wave = cg, t4); xor-tree over waves
        float4 a  = red_s[cg][t4];
        float4 aa = red_ss[cg][t4];
        #pragma unroll
        for (int m = 8; m < 64; m <<= 1) {
            a.x  += __shfl_xor(a.x,  m, 64); a.y  += __shfl_xor(a.y,  m, 64);
            a.z  += __shfl_xor(a.z,  m, 64); a.w  += __shfl_xor(a.w,  m, 64);
            aa.x += __shfl_xor(aa.x, m, 64); aa.y += __shfl_xor(aa.y, m, 64);
            aa.z += __shfl_xor(aa.z, m, 64); aa.w += __shfl_xor(aa.w, m, 64);
        }
        // per-element inclusive scan inside the float4 (double)
        const double d0 = a.x,  d1 = d0 + a.y,  d2 = d1 + a.z,  d3 = d2 + a.w;
        const double e0 = aa.x, e1 = e0 + aa.y, e2 = e1 + aa.z, e3 = e2 + aa.w;
        // inclusive scan across lanes 0..7 (t4 order) of per-slot totals
        double sc_s = d3, sc_ss = e3;
        #pragma unroll
        for (int off = 1; off < 8; off <<= 1) {
            double u = __shfl_up(sc_s,  off, 64);
            double w = __shfl_up(sc_ss, off, 64);
            if (lane >= off) { sc_s += u; sc_ss += w; }
        }
        const double agg_s  = __shfl(sc_s,  7, 64);   // tile total
        const double agg_ss = __shfl(sc_ss, 7, 64);

        // publish aggregate early so successors can look back past us
        if (lane == 0 && j > 0) {
            __hip_atomic_store(&vals[0 * NBLK + rec], agg_s,  __ATOMIC_RELAXED, __HIP_MEMORY_SCOPE_AGENT);
            __hip_atomic_store(&vals[1 * NBLK + rec], agg_ss, __ATOMIC_RELAXED, __HIP_MEMORY_SCOPE_AGENT);
            __hip_atomic_store(&flags[rec], FLAG_AGG, __ATOMIC_RELEASE, __HIP_MEMORY_SCOPE_AGENT);
        }

        // ---- decoupled lookback: 64 predecessors per window ----
        double ps = 0.0, pss = 0.0;
        int hi = j - 1;
        while (hi >= 0) {
            const int p = hi - lane;       // lane 0 = nearest predecessor
            int f = 0;
            if (p >= 0) {
                const int fr = b * NT_ + p;
                do {
                    f = __hip_atomic_load(&flags[fr], __ATOMIC_ACQUIRE, __HIP_MEMORY_SCOPE_AGENT);
                    if (f == 0) __builtin_amdgcn_s_sleep(2);
                } while (f == 0);
            }
            const unsigned long long m2 = __ballot(p >= 0 && f == FLAG_INC);
            const int stop = m2 ? (__ffsll((unsigned long long)m2) - 1) : 64;
            double vs = 0.0, vss = 0.0;
            if (p >= 0 && lane <= stop) {
                const int fr = b * NT_ + p;
                if (lane == stop) {   // nearest tile with full inclusive prefix
                    vs  = __hip_atomic_load(&vals[2 * NBLK + fr], __ATOMIC_RELAXED, __HIP_MEMORY_SCOPE_AGENT);
                    vss = __hip_atomic_load(&vals[3 * NBLK + fr], __ATOMIC_RELAXED, __HIP_MEMORY_SCOPE_AGENT);
                } else {
                    vs  = __hip_atomic_load(&vals[0 * NBLK + fr], __ATOMIC_RELAXED, __HIP_MEMORY_SCOPE_AGENT);
                    vss = __hip_atomic_load(&vals[1 * NBLK + fr], __ATOMIC_RELAXED, __HIP_MEMORY_SCOPE_AGENT);
                }
            }
            ps  += wave_sum(vs);
            pss += wave_sum(vss);
            if (m2) break;
            hi -= 64;
        }

        // publish inclusive prefix ASAP to unblock successors
        if (lane == 0) {
            __hip_atomic_store(&vals[2 * NBLK + rec], ps + agg_s,   __ATOMIC_RELAXED, __HIP_MEMORY_SCOPE_AGENT);
            __hip_atomic_store(&vals[3 * NBLK + rec], pss + agg_ss, __ATOMIC_RELAXED, __HIP_MEMORY_SCOPE_AGENT);
            __hip_atomic_store(&flags[rec], FLAG_INC, __ATOMIC_RELEASE, __HIP_MEMORY_SCOPE_AGENT);
        }

        // mean / rstd for the 32 t of this tile (double, like the old scan)
        if (lane < 8) {
            const double ex_s  = ps  + (sc_s  - d3);   // exclusive before this slot
            const double ex_ss = pss + (sc_ss - e3);
            const int tg = j * TILE + t4 * 4;          // global t of element 0
            float4 mv, rv;
            {
                const double div = 512.0 * (double)(tg + 1);
                const double m = (ex_s + d0) / div, q = (ex_ss + e0) / div;
                mv.x = (float)m; rv.x = (float)(1.0 / sqrt(q - m * m + 1e-8));
            }
            {
                const double div = 512.0 * (double)(tg + 2);
                const double m = (ex_s + d1) / div, q = (ex_ss + e1) / div;
                mv.y = (float)m; rv.y = (float)(1.0 / sqrt(q - m * m + 1e-8));
            }
            {
                const double div = 512.0 * (double)(tg + 3);
                const double m = (ex_s + d2) / div, q = (ex_ss + e2) / div;
                mv.z = (float)m; rv.z = (float)(1.0 / sqrt(q - m * m + 1e-8));
            }
            {
                const double div = 512.0 * (double)(tg + 4);
                const double m = (ex_s + d3) / div, q = (ex_ss + e3) / div;
                mv.w = (float)m; rv.w = (float)(1.0 / sqrt(q - m * m + 1e-8));
            }
            sh_mean[t4] = mv; sh_rstd[t4] = rv;
        }
    }
    __syncthreads();

    // ---- normalize from registers and store ----
    const float4 mv = sh_mean[t4];
    const float4 rv = sh_rstd[t4];
    float4* o4 = (float4*)out;
    #pragma unroll
    for (int p = 0; p < 8; ++p) {
        const int c = p * 64 + cbase;
        const float g  = gains[c];    // L1/L2-hot: 512 floats shared by all blocks
        const float bi = bias[c];
        const float4 xv = v[p];
        float4 ov;
        ov.x = (xv.x - mv.x) * rv.x * g + bi;
        ov.y = (xv.y - mv.y) * rv.y * g + bi;
        ov.z = (xv.z - mv.z) * rv.z * g + bi;
        ov.w = (xv.w - mv.w) * rv.w * g + bi;
        o4[(size_t)(b * C_ + c) * T4_ + tcol] = ov;
    }
}

extern "C" void kernel_launch(void* const* d_in, const int* in_sizes, int n_in,
                              void* d_out, int out_size, void* d_ws, size_t ws_size,
                              hipStream_t stream) {
    const float* x     = (const float*)d_in[0];
    const float* gains = (const float*)d_in[1];
    const float* bias  = (const float*)d_in[2];
    float* out = (float*)d_out;

    char* ws = (char*)d_ws;
    int* flags            = (int*)ws;                               // 16 KB
    unsigned int* ticket  = (unsigned int*)(ws + NBLK * sizeof(int));
    double* vals          = (double*)(ws + 32768);                  // 128 KB

    // zero flags + ticket each launch (ws is poisoned between iterations)
    hipMemsetAsync(d_ws, 0, NBLK * sizeof(int) + sizeof(unsigned int), stream);

    fused_cumnorm<<<NBLK, NTHR, 0, stream>>>(x, gains, bias, out,
                                             flags, ticket, vals);
}

// Round 2
// 478.805 us; speedup vs baseline: 1.8239x; 1.8239x over previous
//
#include <hip/hip_runtime.h>
#include <math.h>

#define B_     16
#define C_     512
#define T_     8192
#define T4_    (T_/4)         // 2048 float4 per (b,c) row
#define SEG_T  128            // t per block
#define SEG_T4 (SEG_T/4)      // 32 float4 columns per block
#define NSEG   (T_/SEG_T)     // 64 segments per batch chain
#define NTHR   512

__device__ __forceinline__ double wave_sum64(double v) {
    #pragma unroll
    for (int m = 1; m < 64; m <<= 1) v += __shfl_xor(v, m, 64);
    return v;
}

// ---------------------------------------------------------------------------
// K1: per-(b,seg) block. Reads its 512C x 128t tile of x once (coalesced
// 512B bursts), reduces over channels, emits:
//   psum : per-t (s, ss) in fp32   -> [2][B][T]   (1 MB)
//   tot  : per-seg (S, SS) double  -> [B][NSEG][2] (16 KB)
// No atomics, no cross-block dependencies.
// ---------------------------------------------------------------------------
extern "C" __global__ void __launch_bounds__(NTHR)
sums_kernel(const float* __restrict__ x,
            float* __restrict__ psum,
            double* __restrict__ tot)
{
    const int seg = blockIdx.x;
    const int b   = blockIdx.y;
    const int tid = threadIdx.x;
    const int t4  = tid & 31;          // float4 column within segment
    const int cg  = tid >> 5;          // 0..15 channel subgroup

    __shared__ float4 sh_s[16][32];
    __shared__ float4 sh_ss[16][32];

    const float4* x4 = (const float4*)x
                     + (size_t)b * C_ * T4_ + (size_t)seg * SEG_T4;

    float4 s  = make_float4(0.f, 0.f, 0.f, 0.f);
    float4 ss = make_float4(0.f, 0.f, 0.f, 0.f);
    #pragma unroll 8
    for (int k = 0; k < C_ / 16; ++k) {
        const int c = cg + k * 16;
        float4 v = x4[(size_t)c * T4_ + t4];
        s.x  += v.x;       s.y  += v.y;       s.z  += v.z;       s.w  += v.w;
        ss.x += v.x * v.x; ss.y += v.y * v.y; ss.z += v.z * v.z; ss.w += v.w * v.w;
    }
    sh_s[cg][t4]  = s;
    sh_ss[cg][t4] = ss;
    __syncthreads();

    if (tid < 64) {  // wave 0 finishes the block
        float4 a  = make_float4(0.f, 0.f, 0.f, 0.f);
        float4 aa = make_float4(0.f, 0.f, 0.f, 0.f);
        if (tid < 32) {
            #pragma unroll
            for (int g2 = 0; g2 < 16; ++g2) {
                float4 u = sh_s[g2][tid];
                float4 w = sh_ss[g2][tid];
                a.x  += u.x; a.y  += u.y; a.z  += u.z; a.w  += u.w;
                aa.x += w.x; aa.y += w.y; aa.z += w.z; aa.w += w.w;
            }
            // per-t channel sums (fp32), float4-coalesced
            ((float4*)psum)[(size_t)b * T4_ + seg * SEG_T4 + tid] = a;
            ((float4*)psum)[(size_t)B_ * T4_ + (size_t)b * T4_ + seg * SEG_T4 + tid] = aa;
        }
        // segment totals in double (lanes >= 32 contribute 0)
        double ds  = (double)a.x  + a.y  + a.z  + a.w;
        double dss = (double)aa.x + aa.y + aa.z + aa.w;
        ds  = wave_sum64(ds);
        dss = wave_sum64(dss);
        if (tid == 0) {
            tot[(size_t)(b * NSEG + seg) * 2 + 0] = ds;
            tot[(size_t)(b * NSEG + seg) * 2 + 1] = dss;
        }
    }
}

// ---------------------------------------------------------------------------
// K2: same grid. Exclusive prefix over seg totals (one 64-lane reduce, no
// loop: NSEG == 64), double-precision scan of own 128 per-t sums, then
// re-read x and write normalized output.
// ---------------------------------------------------------------------------
extern "C" __global__ void __launch_bounds__(NTHR)
norm_kernel(const float* __restrict__ x,
            const float* __restrict__ gains,
            const float* __restrict__ bias,
            const float* __restrict__ psum,
            const double* __restrict__ tot,
            float* __restrict__ out)
{
    const int seg = blockIdx.x;
    const int b   = blockIdx.y;
    const int tid = threadIdx.x;
    const int t4  = tid & 31;
    const int cg  = tid >> 5;

    __shared__ float  sh_g[C_], sh_b[C_];
    __shared__ float4 sh_mean[32], sh_rstd[32];

    sh_g[tid] = gains[tid];   // NTHR == C_ == 512
    sh_b[tid] = bias[tid];

    if (tid < 64) {  // wave 0: prefix + scan + mean/rstd
        // exclusive prefix of segment totals: lane i holds tot[seg' = i] if i < seg
        double ps = 0.0, pss = 0.0;
        if (tid < seg) {
            ps  = tot[(size_t)(b * NSEG + tid) * 2 + 0];
            pss = tot[(size_t)(b * NSEG + tid) * 2 + 1];
        }
        ps  = wave_sum64(ps);    // all lanes now hold sum of totals before seg
        pss = wave_sum64(pss);

        float4 a  = make_float4(0.f, 0.f, 0.f, 0.f);
        float4 aa = make_float4(0.f, 0.f, 0.f, 0.f);
        if (tid < 32) {
            a  = ((const float4*)psum)[(size_t)b * T4_ + seg * SEG_T4 + tid];
            aa = ((const float4*)psum)[(size_t)B_ * T4_ + (size_t)b * T4_ + seg * SEG_T4 + tid];
        }
        // inclusive scan: inside the float4 (double) ...
        const double d0 = a.x,  d1 = d0 + a.y,  d2 = d1 + a.z,  d3 = d2 + a.w;
        const double e0 = aa.x, e1 = e0 + aa.y, e2 = e1 + aa.z, e3 = e2 + aa.w;
        // ... then across the 32 lanes (slot totals)
        double sc_s = d3, sc_ss = e3;
        #pragma unroll
        for (int off = 1; off < 32; off <<= 1) {
            double u = __shfl_up(sc_s,  off, 64);
            double w = __shfl_up(sc_ss, off, 64);
            if (tid >= off && tid < 32) { sc_s += u; sc_ss += w; }
        }
        if (tid < 32) {
            const double ex_s  = ps  + (sc_s  - d3);  // exclusive before this float4
            const double ex_ss = pss + (sc_ss - e3);
            const int tg = seg * SEG_T + tid * 4;     // global t of element 0
            float4 mv, rv;
            {
                const double div = 512.0 * (double)(tg + 1);
                const double m = (ex_s + d0) / div, q = (ex_ss + e0) / div;
                mv.x = (float)m; rv.x = (float)(1.0 / sqrt(q - m * m + 1e-8));
            }
            {
                const double div = 512.0 * (double)(tg + 2);
                const double m = (ex_s + d1) / div, q = (ex_ss + e1) / div;
                mv.y = (float)m; rv.y = (float)(1.0 / sqrt(q - m * m + 1e-8));
            }
            {
                const double div = 512.0 * (double)(tg + 3);
                const double m = (ex_s + d2) / div, q = (ex_ss + e2) / div;
                mv.z = (float)m; rv.z = (float)(1.0 / sqrt(q - m * m + 1e-8));
            }
            {
                const double div = 512.0 * (double)(tg + 4);
                const double m = (ex_s + d3) / div, q = (ex_ss + e3) / div;
                mv.w = (float)m; rv.w = (float)(1.0 / sqrt(q - m * m + 1e-8));
            }
            sh_mean[tid] = mv;
            sh_rstd[tid] = rv;
        }
    }
    __syncthreads();

    const float4 mv = sh_mean[t4];
    const float4 rv = sh_rstd[t4];
    const float4* x4 = (const float4*)x
                     + (size_t)b * C_ * T4_ + (size_t)seg * SEG_T4;
    float4* o4 = (float4*)out
               + (size_t)b * C_ * T4_ + (size_t)seg * SEG_T4;

    #pragma unroll 8
    for (int k = 0; k < C_ / 16; ++k) {
        const int c = cg + k * 16;
        const float g  = sh_g[c];
        const float bi = sh_b[c];
        float4 v = x4[(size_t)c * T4_ + t4];
        float4 o;
        o.x = (v.x - mv.x) * rv.x * g + bi;
        o.y = (v.y - mv.y) * rv.y * g + bi;
        o.z = (v.z - mv.z) * rv.z * g + bi;
        o.w = (v.w - mv.w) * rv.w * g + bi;
        o4[(size_t)c * T4_ + t4] = o;
    }
}

extern "C" void kernel_launch(void* const* d_in, const int* in_sizes, int n_in,
                              void* d_out, int out_size, void* d_ws, size_t ws_size,
                              hipStream_t stream) {
    const float* x     = (const float*)d_in[0];
    const float* gains = (const float*)d_in[1];
    const float* bias  = (const float*)d_in[2];
    float* out = (float*)d_out;

    char* ws = (char*)d_ws;
    float*  psum = (float*)ws;                                   // 2*B*T floats = 1 MB
    double* tot  = (double*)(ws + (size_t)2 * B_ * T_ * sizeof(float)); // 16 KB

    dim3 grid(NSEG, B_);   // 1024 blocks
    sums_kernel<<<grid, NTHR, 0, stream>>>(x, psum, tot);
    norm_kernel<<<grid, NTHR, 0, stream>>>(x, gains, bias, psum, tot, out);
}

// Round 4
// 461.358 us; speedup vs baseline: 1.8929x; 1.0378x over previous
//
#include <hip/hip_runtime.h>
#include <math.h>

#define B_     16
#define C_     512
#define T_     8192
#define T4_    (T_/4)         // 2048 float4 per (b,c) row
#define SEG_T  128            // t per block
#define SEG_T4 (SEG_T/4)      // 32 float4 columns per block
#define NSEG   (T_/SEG_T)     // 64 segments per batch chain
#define NTHR   512

// native clang vector type for nontemporal builtins (HIP float4 is a class)
typedef float vfloat4 __attribute__((ext_vector_type(4)));

__device__ __forceinline__ double wave_sum64(double v) {
    #pragma unroll
    for (int m = 1; m < 64; m <<= 1) v += __shfl_xor(v, m, 64);
    return v;
}

// ---------------------------------------------------------------------------
// K1: per-(b,seg) block. Reads its 512C x 128t tile of x once (coalesced
// 512B bursts, FORWARD channel order -> late channels stay L3-resident),
// reduces over channels, emits:
//   psum : per-t (s, ss) in fp32   -> [2][B][T]   (1 MB)
//   tot  : per-seg (S, SS) double  -> [B][NSEG][2] (16 KB)
// ---------------------------------------------------------------------------
extern "C" __global__ void __launch_bounds__(NTHR)
sums_kernel(const float* __restrict__ x,
            float* __restrict__ psum,
            double* __restrict__ tot)
{
    const int seg = blockIdx.x;
    const int b   = blockIdx.y;
    const int tid = threadIdx.x;
    const int t4  = tid & 31;          // float4 column within segment
    const int cg  = tid >> 5;          // 0..15 channel subgroup

    __shared__ float4 sh_s[16][32];
    __shared__ float4 sh_ss[16][32];

    const float4* x4 = (const float4*)x
                     + (size_t)b * C_ * T4_ + (size_t)seg * SEG_T4;

    float4 s  = make_float4(0.f, 0.f, 0.f, 0.f);
    float4 ss = make_float4(0.f, 0.f, 0.f, 0.f);
    #pragma unroll 8
    for (int k = 0; k < C_ / 16; ++k) {
        const int c = cg + k * 16;
        float4 v = x4[(size_t)c * T4_ + t4];
        s.x  += v.x;       s.y  += v.y;       s.z  += v.z;       s.w  += v.w;
        ss.x += v.x * v.x; ss.y += v.y * v.y; ss.z += v.z * v.z; ss.w += v.w * v.w;
    }
    sh_s[cg][t4]  = s;
    sh_ss[cg][t4] = ss;
    __syncthreads();

    if (tid < 64) {  // wave 0 finishes the block
        float4 a  = make_float4(0.f, 0.f, 0.f, 0.f);
        float4 aa = make_float4(0.f, 0.f, 0.f, 0.f);
        if (tid < 32) {
            #pragma unroll
            for (int g2 = 0; g2 < 16; ++g2) {
                float4 u = sh_s[g2][tid];
                float4 w = sh_ss[g2][tid];
                a.x  += u.x; a.y  += u.y; a.z  += u.z; a.w  += u.w;
                aa.x += w.x; aa.y += w.y; aa.z += w.z; aa.w += w.w;
            }
            // per-t channel sums (fp32), float4-coalesced
            ((float4*)psum)[(size_t)b * T4_ + seg * SEG_T4 + tid] = a;
            ((float4*)psum)[(size_t)B_ * T4_ + (size_t)b * T4_ + seg * SEG_T4 + tid] = aa;
        }
        // segment totals in double (lanes >= 32 contribute 0)
        double ds  = (double)a.x  + a.y  + a.z  + a.w;
        double dss = (double)aa.x + aa.y + aa.z + aa.w;
        ds  = wave_sum64(ds);
        dss = wave_sum64(dss);
        if (tid == 0) {
            tot[(size_t)(b * NSEG + seg) * 2 + 0] = ds;
            tot[(size_t)(b * NSEG + seg) * 2 + 1] = dss;
        }
    }
}

// ---------------------------------------------------------------------------
// K2: same grid. Exclusive prefix over seg totals (single 64-lane reduce),
// double-precision scan of own 128 per-t sums, then re-read x and write
// normalized output.
//   - channel loop REVERSED: consume L3-resident (recently streamed) lines
//     first, cold misses last  -> defeats the exact-cache-size LRU pathology
//   - x loads non-temporal: cold lines never re-used, don't let them evict
//   - out stores non-temporal: don't let 256 MiB of write-allocate wipe x
// ---------------------------------------------------------------------------
extern "C" __global__ void __launch_bounds__(NTHR)
norm_kernel(const float* __restrict__ x,
            const float* __restrict__ gains,
            const float* __restrict__ bias,
            const float* __restrict__ psum,
            const double* __restrict__ tot,
            float* __restrict__ out)
{
    const int seg = blockIdx.x;
    const int b   = blockIdx.y;
    const int tid = threadIdx.x;
    const int t4  = tid & 31;
    const int cg  = tid >> 5;

    __shared__ float  sh_g[C_], sh_b[C_];
    __shared__ float4 sh_mean[32], sh_rstd[32];

    sh_g[tid] = gains[tid];   // NTHR == C_ == 512
    sh_b[tid] = bias[tid];

    if (tid < 64) {  // wave 0: prefix + scan + mean/rstd
        // exclusive prefix of segment totals: lane i holds tot[seg' = i] if i < seg
        double ps = 0.0, pss = 0.0;
        if (tid < seg) {
            ps  = tot[(size_t)(b * NSEG + tid) * 2 + 0];
            pss = tot[(size_t)(b * NSEG + tid) * 2 + 1];
        }
        ps  = wave_sum64(ps);    // all lanes now hold sum of totals before seg
        pss = wave_sum64(pss);

        float4 a  = make_float4(0.f, 0.f, 0.f, 0.f);
        float4 aa = make_float4(0.f, 0.f, 0.f, 0.f);
        if (tid < 32) {
            a  = ((const float4*)psum)[(size_t)b * T4_ + seg * SEG_T4 + tid];
            aa = ((const float4*)psum)[(size_t)B_ * T4_ + (size_t)b * T4_ + seg * SEG_T4 + tid];
        }
        // inclusive scan: inside the float4 (double) ...
        const double d0 = a.x,  d1 = d0 + a.y,  d2 = d1 + a.z,  d3 = d2 + a.w;
        const double e0 = aa.x, e1 = e0 + aa.y, e2 = e1 + aa.z, e3 = e2 + aa.w;
        // ... then across the 32 lanes (slot totals)
        double sc_s = d3, sc_ss = e3;
        #pragma unroll
        for (int off = 1; off < 32; off <<= 1) {
            double u = __shfl_up(sc_s,  off, 64);
            double w = __shfl_up(sc_ss, off, 64);
            if (tid >= off && tid < 32) { sc_s += u; sc_ss += w; }
        }
        if (tid < 32) {
            const double ex_s  = ps  + (sc_s  - d3);  // exclusive before this float4
            const double ex_ss = pss + (sc_ss - e3);
            const int tg = seg * SEG_T + tid * 4;     // global t of element 0
            float4 mv, rv;
            {
                const double div = 512.0 * (double)(tg + 1);
                const double m = (ex_s + d0) / div, q = (ex_ss + e0) / div;
                mv.x = (float)m; rv.x = (float)(1.0 / sqrt(q - m * m + 1e-8));
            }
            {
                const double div = 512.0 * (double)(tg + 2);
                const double m = (ex_s + d1) / div, q = (ex_ss + e1) / div;
                mv.y = (float)m; rv.y = (float)(1.0 / sqrt(q - m * m + 1e-8));
            }
            {
                const double div = 512.0 * (double)(tg + 3);
                const double m = (ex_s + d2) / div, q = (ex_ss + e2) / div;
                mv.z = (float)m; rv.z = (float)(1.0 / sqrt(q - m * m + 1e-8));
            }
            {
                const double div = 512.0 * (double)(tg + 4);
                const double m = (ex_s + d3) / div, q = (ex_ss + e3) / div;
                mv.w = (float)m; rv.w = (float)(1.0 / sqrt(q - m * m + 1e-8));
            }
            sh_mean[tid] = mv;
            sh_rstd[tid] = rv;
        }
    }
    __syncthreads();

    const float4 mv = sh_mean[t4];
    const float4 rv = sh_rstd[t4];
    const vfloat4* x4 = (const vfloat4*)x
                      + (size_t)b * C_ * T4_ + (size_t)seg * SEG_T4;
    vfloat4* o4 = (vfloat4*)out
                + (size_t)b * C_ * T4_ + (size_t)seg * SEG_T4;

    // REVERSED channel order: hottest (last-streamed by K1) lines first.
    #pragma unroll 8
    for (int k = C_ / 16 - 1; k >= 0; --k) {
        const int c = cg + k * 16;
        const float g  = sh_g[c];
        const float bi = sh_b[c];
        vfloat4 v = __builtin_nontemporal_load(&x4[(size_t)c * T4_ + t4]);
        vfloat4 o;
        o.x = (v.x - mv.x) * rv.x * g + bi;
        o.y = (v.y - mv.y) * rv.y * g + bi;
        o.z = (v.z - mv.z) * rv.z * g + bi;
        o.w = (v.w - mv.w) * rv.w * g + bi;
        __builtin_nontemporal_store(o, &o4[(size_t)c * T4_ + t4]);
    }
}

extern "C" void kernel_launch(void* const* d_in, const int* in_sizes, int n_in,
                              void* d_out, int out_size, void* d_ws, size_t ws_size,
                              hipStream_t stream) {
    const float* x     = (const float*)d_in[0];
    const float* gains = (const float*)d_in[1];
    const float* bias  = (const float*)d_in[2];
    float* out = (float*)d_out;

    char* ws = (char*)d_ws;
    float*  psum = (float*)ws;                                   // 2*B*T floats = 1 MB
    double* tot  = (double*)(ws + (size_t)2 * B_ * T_ * sizeof(float)); // 16 KB

    dim3 grid(NSEG, B_);   // 1024 blocks
    sums_kernel<<<grid, NTHR, 0, stream>>>(x, psum, tot);
    norm_kernel<<<grid, NTHR, 0, stream>>>(x, gains, bias, psum, tot, out);
}